// Round 8
// baseline (561.362 us; speedup 1.0000x reference)
//
#include <hip/hip_runtime.h>

// ---------------- problem dims ----------------
#define NE   200000
#define DC   64
#define DL   256
#define DD   128
#define FEAT 320          // 2*DD + DC
#define IND  449          // FEAT + DD + 1
#define INDP 512          // ebuf padded row stride (449 -> 512, pad zero-filled)
#define DH   80
#define BB   32
#define TT   64
#define NEV  2048         // BB*TT
#define NSLOT 4096

typedef __attribute__((ext_vector_type(4))) float  floatx4;
typedef __attribute__((ext_vector_type(4), aligned(4))) float floatx4u;   // dword-aligned vec4

__device__ __forceinline__ float sigmoidf_(float x) { return 1.0f / (1.0f + __expf(-x)); }

// ---------------- K0: output-state init copy (mem0 -> out_mem, lt0 -> out_lt) ----------
// Three alignment variants all pinned at 62us/2.5TB/s -> alignment is not the limit.
// This version adds (a) 4x unroll: 8 nt-loads in flight, then 4 nt-stores;
// (b) nontemporal hints (streamed-once data, skip cache allocation).
__global__ __launch_bounds__(256)
void copy_init(const float* __restrict__ mem0, const float* __restrict__ lt0,
               float* __restrict__ out_mem, float* __restrict__ out_lt) {
    const size_t NM = (size_t)NE * DD;          // 25,600,000
    const size_t NL = (size_t)NE;               // 200,000
    size_t gid = (size_t)blockIdx.x * 256 + threadIdx.x;
    size_t stride = (size_t)gridDim.x * 256;
    if (gid == 0) {
        out_mem[0] = mem0[0]; out_mem[1] = mem0[1]; out_mem[2] = mem0[2];
        out_mem[NM - 1] = mem0[NM - 1];
        out_lt[0] = lt0[0]; out_lt[1] = lt0[1]; out_lt[2] = lt0[2];
        out_lt[NL - 1] = lt0[NL - 1];
    }
    const size_t nm4 = (NM - 4) / 4;            // 6,399,999 vec4 stores over [3, NM-1)
    float* __restrict__ dm = out_mem + 3;       // 16B-aligned
    size_t i = gid;
    for (; i + 3 * stride < nm4; i += 4 * stride) {
        size_t i0 = i, i1 = i + stride, i2 = i + 2 * stride, i3 = i + 3 * stride;
        floatx4 lo0 = __builtin_nontemporal_load((const floatx4*)&mem0[i0 * 4]);
        floatx4 hi0 = __builtin_nontemporal_load((const floatx4*)&mem0[i0 * 4 + 4]);
        floatx4 lo1 = __builtin_nontemporal_load((const floatx4*)&mem0[i1 * 4]);
        floatx4 hi1 = __builtin_nontemporal_load((const floatx4*)&mem0[i1 * 4 + 4]);
        floatx4 lo2 = __builtin_nontemporal_load((const floatx4*)&mem0[i2 * 4]);
        floatx4 hi2 = __builtin_nontemporal_load((const floatx4*)&mem0[i2 * 4 + 4]);
        floatx4 lo3 = __builtin_nontemporal_load((const floatx4*)&mem0[i3 * 4]);
        floatx4 hi3 = __builtin_nontemporal_load((const floatx4*)&mem0[i3 * 4 + 4]);
        floatx4 o0 = {lo0[3], hi0[0], hi0[1], hi0[2]};
        floatx4 o1 = {lo1[3], hi1[0], hi1[1], hi1[2]};
        floatx4 o2 = {lo2[3], hi2[0], hi2[1], hi2[2]};
        floatx4 o3 = {lo3[3], hi3[0], hi3[1], hi3[2]};
        __builtin_nontemporal_store(o0, (floatx4*)&dm[i0 * 4]);
        __builtin_nontemporal_store(o1, (floatx4*)&dm[i1 * 4]);
        __builtin_nontemporal_store(o2, (floatx4*)&dm[i2 * 4]);
        __builtin_nontemporal_store(o3, (floatx4*)&dm[i3 * 4]);
    }
    for (; i < nm4; i += stride) {
        floatx4 lo = __builtin_nontemporal_load((const floatx4*)&mem0[i * 4]);
        floatx4 hi = __builtin_nontemporal_load((const floatx4*)&mem0[i * 4 + 4]);
        floatx4 o = {lo[3], hi[0], hi[1], hi[2]};
        __builtin_nontemporal_store(o, (floatx4*)&dm[i * 4]);
    }
    const size_t nl4 = (NL - 4) / 4;            // 49,999
    float* __restrict__ dl = out_lt + 3;        // 16B-aligned
    for (size_t j = gid; j < nl4; j += stride) {
        floatx4 lo = __builtin_nontemporal_load((const floatx4*)&lt0[j * 4]);
        floatx4 hi = __builtin_nontemporal_load((const floatx4*)&lt0[j * 4 + 4]);
        floatx4 o = {lo[3], hi[0], hi[1], hi[2]};
        __builtin_nontemporal_store(o, (floatx4*)&dl[j * 4]);
    }
}

// ---------------- K1: slot analysis (prev-toucher, dt, winner) ----------------
__global__ __launch_bounds__(256)
void slot_analyze(const int* __restrict__ seq_s, const int* __restrict__ seq_o,
                  const float* __restrict__ seq_time, const float* __restrict__ lt0,
                  float* __restrict__ slotDt, int* __restrict__ slotPrev,
                  int* __restrict__ slotWin) {
    __shared__ int entL[NSLOT];
    int tid = threadIdx.x;
    for (int j = tid; j < NSLOT; j += 256) {
        int b = j & 31, side = (j >> 5) & 1, t = j >> 6;
        entL[j] = (side ? seq_o : seq_s)[b * TT + t];
    }
    __syncthreads();
    int wave = tid >> 6, lane = tid & 63;
    int slot = blockIdx.x * 4 + wave;
    int t = slot >> 6;
    int myent = entL[slot];
    int win = 1, best = -1;
#pragma unroll 8
    for (int jj = 0; jj < NSLOT / 64; ++jj) {
        int j = jj * 64 + lane;
        if (entL[j] == myent) {
            if (j > slot) win = 0;
            else if ((j >> 6) < t && j > best) best = j;   // keeps max key among prior steps
        }
    }
#pragma unroll
    for (int off = 32; off; off >>= 1) {
        int ob = __shfl_xor(best, off, 64);
        best = best > ob ? best : ob;
    }
    win = __all(win);
    if (lane == 0) {
        int b = slot & 31;
        float tv = seq_time[b * TT + t];
        float pt = (best >= 0) ? seq_time[(best & 31) * TT + (best >> 6)] : lt0[myent];
        slotDt[slot]   = tv - pt;
        slotPrev[slot] = best;
        slotWin[slot]  = win;
    }
}

// ---------------- K1b: build fix list ----------------
__global__ __launch_bounds__(256)
void fixlist_build(const int* __restrict__ slotPrev, int* __restrict__ fixList,
                   int* __restrict__ fixState, int* __restrict__ evFixIdx,
                   int* __restrict__ fixCnt) {
    int e = blockIdx.x * 256 + threadIdx.x;   // 2048 events
    int b = e >> 6, t = e & 63;
    int c = (slotPrev[t * 64 + b] >= 0) | (slotPrev[t * 64 + 32 + b] >= 0);
    int idx = -1;
    if (c) { idx = atomicAdd(fixCnt, 1); fixList[idx] = e; fixState[idx] = -1; }
    evFixIdx[e] = idx;
}

// ---------------- K2: all-events parallel RNN compute (fp32) ----------------
__global__ __launch_bounds__(256)
void event_compute(const int* __restrict__ seq_s, const int* __restrict__ seq_o,
                   const int* __restrict__ seq_r, const float* __restrict__ seq_time,
                   const float* __restrict__ mem0, const float* __restrict__ rel,
                   const float* __restrict__ W_hidden, const float* __restrict__ W_hh,
                   const float* __restrict__ W_st, const float* __restrict__ W_ot,
                   const float* __restrict__ slotDt,
                   float* __restrict__ evt, float* __restrict__ ebuf) {
    __shared__ float xc[8][FEAT];
    __shared__ float hs[8][DL];
    __shared__ int   sSi[8], sOi[8], sRi[8];
    __shared__ float sDs[8], sDo[8], sTv[8];
    int tid = threadIdx.x;
    int e0 = blockIdx.x * 8;
    if (tid < 8) {
        int e = e0 + tid;
        sSi[tid] = seq_s[e]; sOi[tid] = seq_o[e]; sRi[tid] = seq_r[e];
        int b = e >> 6, t = e & 63;
        sDs[tid] = slotDt[t * 64 + b];
        sDo[tid] = slotDt[t * 64 + 32 + b];
        sTv[tid] = seq_time[e];
    }
    __syncthreads();
    for (int i = tid; i < 8 * FEAT; i += 256) {
        int r = i / FEAT, k = i - r * FEAT;
        float v;
        if (k < DD)            v = mem0[(size_t)sSi[r] * DD + k];
        else if (k < 2 * DD)   v = mem0[(size_t)sOi[r] * DD + (k - DD)];
        else                   v = rel[(size_t)sRi[r] * DC + (k - 2 * DD)];
        xc[r][k] = v;
    }
    __syncthreads();
    {   // z = xc @ W_hidden ; h = sigmoid(z)
        int j = tid;
        float acc[8] = {0.f,0.f,0.f,0.f,0.f,0.f,0.f,0.f};
        for (int k = 0; k < FEAT; ++k) {
            float w = W_hidden[(size_t)k * DL + j];
#pragma unroll
            for (int r = 0; r < 8; ++r) acc[r] += xc[r][k] * w;
        }
#pragma unroll
        for (int r = 0; r < 8; ++r) hs[r][j] = sigmoidf_(acc[r]);
    }
    __syncthreads();
    {   // hh = h @ W_hh ; ns/no = sigmoid(dt*W + hh)
        int d = tid & 127, grp = tid >> 7;
        float acc[4] = {0.f,0.f,0.f,0.f};
        for (int l = 0; l < DL; ++l) {
            float w = W_hh[(size_t)l * DD + d];
#pragma unroll
            for (int rr = 0; rr < 4; ++rr) acc[rr] += hs[grp * 4 + rr][l] * w;
        }
        float wst = W_st[d], wot = W_ot[d];
#pragma unroll
        for (int rr = 0; rr < 4; ++rr) {
            int r = grp * 4 + rr;
            int e = e0 + r;
            float ns  = sigmoidf_(sDs[r] * wst + acc[rr]);
            float no_ = sigmoidf_(sDo[r] * wot + acc[rr]);
            evt[(size_t)e * FEAT + d]      = ns;
            evt[(size_t)e * FEAT + DD + d] = no_;
            ebuf[(size_t)e * INDP + d]      = ns;
            ebuf[(size_t)e * INDP + DD + d] = no_;
        }
    }
    for (int i = tid; i < 8 * DC; i += 256) {
        int r = i >> 6, c = i & 63;
        float v = xc[r][2 * DD + c];
        int e = e0 + r;
        evt[(size_t)e * FEAT + 2 * DD + c] = v;
        ebuf[(size_t)e * INDP + 2 * DD + c] = v;
    }
    for (int i = tid; i < 8 * DD; i += 256) {
        int r = i >> 7, d = i & 127;
        float denom = __powf(1.0e4f, (float)d);     // inf for d>=10 -> 1/inf = 0 (matches ref)
        float v = sinf(sTv[r] * (1.0f / denom));
        int e = e0 + r;
        ebuf[(size_t)e * INDP + FEAT + d] = v;
    }
    if (tid < 8) ebuf[(size_t)(e0 + tid) * INDP + FEAT + DD] = 1.0f;
}

// ---------------- K3: fix rounds ----------------
__global__ __launch_bounds__(256)
void fix_round(int round,
               const int* __restrict__ seq_s, const int* __restrict__ seq_o,
               const float* __restrict__ mem0, const float* __restrict__ W_hidden,
               const float* __restrict__ W_hh, const float* __restrict__ W_st,
               const float* __restrict__ W_ot, const float* __restrict__ slotDt,
               const int* __restrict__ slotPrev, const int* __restrict__ fixList,
               int* __restrict__ fixState, const int* __restrict__ evFixIdx,
               const int* __restrict__ fixCnt,
               float* __restrict__ evt, float* __restrict__ ebuf) {
    __shared__ float xc[FEAT];
    __shared__ float hsv[DL];
    __shared__ float hp[2][DD];
    __shared__ int sGo, sPs, sPo, sE;
    int tid = threadIdx.x;
    int n = *fixCnt;
    for (int f = blockIdx.x; f < n; f += gridDim.x) {
        if (tid == 0) {
            int go = 0, ps = 0, po = 0, e = 0;
            if (fixState[f] == -1) {
                e = fixList[f];
                int b = e >> 6, t = e & 63;
                ps = slotPrev[t * 64 + b];
                po = slotPrev[t * 64 + 32 + b];
                go = 1;
                if (ps >= 0) {
                    int pe = (ps & 31) * 64 + (ps >> 6);
                    int fi = evFixIdx[pe];
                    if (fi >= 0) { int st = fixState[fi]; if (st < 0 || st >= round) go = 0; }
                }
                if (po >= 0) {
                    int pe = (po & 31) * 64 + (po >> 6);
                    int fi = evFixIdx[pe];
                    if (fi >= 0) { int st = fixState[fi]; if (st < 0 || st >= round) go = 0; }
                }
            }
            sGo = go; sPs = ps; sPo = po; sE = e;
        }
        __syncthreads();
        int go = sGo, ps = sPs, po = sPo, e = sE;
        __syncthreads();
        if (!go) continue;
        int b = e >> 6, t = e & 63;
        for (int i = tid; i < FEAT; i += 256) {
            float v;
            if (i < DD) {
                v = (ps >= 0) ? evt[(size_t)((ps & 31) * 64 + (ps >> 6)) * FEAT + ((ps >> 5) & 1) * DD + i]
                              : mem0[(size_t)seq_s[e] * DD + i];
            } else if (i < 2 * DD) {
                int k = i - DD;
                v = (po >= 0) ? evt[(size_t)((po & 31) * 64 + (po >> 6)) * FEAT + ((po >> 5) & 1) * DD + k]
                              : mem0[(size_t)seq_o[e] * DD + k];
            } else {
                v = evt[(size_t)e * FEAT + i];
            }
            xc[i] = v;
        }
        __syncthreads();
        {
            float a0 = 0.f, a1 = 0.f, a2 = 0.f, a3 = 0.f;
            for (int k = 0; k < FEAT; k += 4) {
                a0 += xc[k]     * W_hidden[(size_t)k * DL + tid];
                a1 += xc[k + 1] * W_hidden[(size_t)(k + 1) * DL + tid];
                a2 += xc[k + 2] * W_hidden[(size_t)(k + 2) * DL + tid];
                a3 += xc[k + 3] * W_hidden[(size_t)(k + 3) * DL + tid];
            }
            hsv[tid] = sigmoidf_((a0 + a1) + (a2 + a3));
        }
        __syncthreads();
        {
            int d = tid & 127, g = tid >> 7;
            float a0 = 0.f, a1 = 0.f;
            int l0 = g * 128;
            for (int l = 0; l < 128; l += 2) {
                a0 += hsv[l0 + l]     * W_hh[(size_t)(l0 + l) * DD + d];
                a1 += hsv[l0 + l + 1] * W_hh[(size_t)(l0 + l + 1) * DD + d];
            }
            hp[g][d] = a0 + a1;
        }
        __syncthreads();
        if (tid < DD) {
            float hh = hp[0][tid] + hp[1][tid];
            float ns  = sigmoidf_(slotDt[t * 64 + b]      * W_st[tid] + hh);
            float no_ = sigmoidf_(slotDt[t * 64 + 32 + b] * W_ot[tid] + hh);
            evt[(size_t)e * FEAT + tid]      = ns;
            evt[(size_t)e * FEAT + DD + tid] = no_;
            ebuf[(size_t)e * INDP + tid]      = ns;
            ebuf[(size_t)e * INDP + DD + tid] = no_;
        }
        __syncthreads();
        __threadfence();
        if (tid == 0) fixState[f] = round;
        __syncthreads();
    }
}

// ---------------- K4: winner scatter to out_mem / out_lt ----------------
__global__ __launch_bounds__(256)
void scatter_win(const int* __restrict__ seq_s, const int* __restrict__ seq_o,
                 const float* __restrict__ seq_time, const int* __restrict__ slotWin,
                 const float* __restrict__ evt, float* __restrict__ out_mem,
                 float* __restrict__ out_lt) {
    int gid = blockIdx.x * 256 + threadIdx.x;   // 131072 = 4096 slots * 32
    int slot = gid >> 5, c = gid & 31;
    if (!slotWin[slot]) return;
    int b = slot & 31, side = (slot >> 5) & 1, t = slot >> 6;
    int e = b * TT + t;
    int ent = (side ? seq_o : seq_s)[e];
    floatx4 v = *(const floatx4*)&evt[(size_t)e * FEAT + side * DD + c * 4];
    *(floatx4u*)&out_mem[(size_t)ent * DD + c * 4] = v;
    if (c == 0) out_lt[ent] = seq_time[e];
}

// ---------------- phase 2: split-K latency-optimized GEMMs ----------------
// proj: C[2048][320] = A[2048][512(INDP)] @ W[449][320] for z in {q,k,v}.
__global__ __launch_bounds__(128)
void proj(const float* __restrict__ ebuf, const float* __restrict__ Wq,
          const float* __restrict__ Wk, const float* __restrict__ Wv,
          float* __restrict__ q, float* __restrict__ k, float* __restrict__ v) {
    __shared__ float AsT[2][32][33];   // [wave][kk][r]
    __shared__ float Bs[2][32][36];    // [wave][kk][c]
    __shared__ float comb[32][36];
    const float* W = (blockIdx.z == 0) ? Wq : (blockIdx.z == 1) ? Wk : Wv;
    float* out = (blockIdx.z == 0) ? q : (blockIdx.z == 1) ? k : v;
    int tid = threadIdx.x;
    int w = tid >> 6, lane = tid & 63;
    int row0 = blockIdx.x * 32, col0 = blockIdx.y * 32;
    int tx = lane & 7, ty = lane >> 3;
    const int sr = lane >> 3, sk4 = (lane & 7) * 4;
    const int IT0 = w * 8, IT1 = IT0 + 8;       // 16 iters total (K=512 padded)
    floatx4 aR[4], bR[4], acc[4];
#pragma unroll
    for (int i = 0; i < 4; ++i) acc[i] = (floatx4){0.f, 0.f, 0.f, 0.f};
#pragma unroll
    for (int m = 0; m < 4; ++m) {
        int r = m * 8 + sr;
        int kg = IT0 * 32 + r;
        aR[m] = *(const floatx4*)&ebuf[(size_t)(row0 + r) * INDP + IT0 * 32 + sk4];
        bR[m] = (kg < IND) ? *(const floatx4*)&W[(size_t)kg * FEAT + col0 + sk4]
                           : (floatx4){0.f, 0.f, 0.f, 0.f};
    }
    for (int it = IT0; it < IT1; ++it) {
        __syncthreads();
#pragma unroll
        for (int m = 0; m < 4; ++m) {
            int r = m * 8 + sr;
            AsT[w][sk4 + 0][r] = aR[m][0];
            AsT[w][sk4 + 1][r] = aR[m][1];
            AsT[w][sk4 + 2][r] = aR[m][2];
            AsT[w][sk4 + 3][r] = aR[m][3];
            *(floatx4*)&Bs[w][r][sk4] = bR[m];
        }
        __syncthreads();
        if (it + 1 < IT1) {                      // prefetch next tile (overlaps compute)
            int k0n = (it + 1) * 32;
#pragma unroll
            for (int m = 0; m < 4; ++m) {
                int r = m * 8 + sr;
                int kg = k0n + r;
                aR[m] = *(const floatx4*)&ebuf[(size_t)(row0 + r) * INDP + k0n + sk4];
                bR[m] = (kg < IND) ? *(const floatx4*)&W[(size_t)kg * FEAT + col0 + sk4]
                                   : (floatx4){0.f, 0.f, 0.f, 0.f};
            }
        }
#pragma unroll
        for (int kk = 0; kk < 32; ++kk) {
            floatx4 a = *(const floatx4*)&AsT[w][kk][ty * 4];
            floatx4 b = *(const floatx4*)&Bs[w][kk][tx * 4];
#pragma unroll
            for (int i = 0; i < 4; ++i) acc[i] += a[i] * b;
        }
    }
    if (w == 1) {
#pragma unroll
        for (int i = 0; i < 4; ++i)
            *(floatx4*)&comb[ty * 4 + i][tx * 4] = acc[i];
    }
    __syncthreads();
    if (w == 0) {
#pragma unroll
        for (int i = 0; i < 4; ++i) {
            floatx4 p = *(const floatx4*)&comb[ty * 4 + i][tx * 4];
            floatx4 s = acc[i] + p;
            *(floatx4*)&out[(size_t)(row0 + ty * 4 + i) * FEAT + col0 + tx * 4] = s;
        }
    }
}

// outproj: acc = A[2048][320] @ Wo[320][320]; x = resid + tanh(acc); optional ebuf write.
__global__ __launch_bounds__(128)
void outproj(const float* __restrict__ ain, const float* __restrict__ Wo,
             const float* __restrict__ resid, float* __restrict__ xout,
             float* __restrict__ ebufW, int writeE) {
    __shared__ float AsT[2][32][33];
    __shared__ float Bs[2][32][36];
    __shared__ float comb[32][36];
    int tid = threadIdx.x;
    int w = tid >> 6, lane = tid & 63;
    int row0 = blockIdx.x * 32, col0 = blockIdx.y * 32;
    int tx = lane & 7, ty = lane >> 3;
    const int sr = lane >> 3, sk4 = (lane & 7) * 4;
    const int IT0 = w * 5, IT1 = IT0 + 5;       // 10 iters total (K=320 exact)
    floatx4 aR[4], bR[4], acc[4];
#pragma unroll
    for (int i = 0; i < 4; ++i) acc[i] = (floatx4){0.f, 0.f, 0.f, 0.f};
#pragma unroll
    for (int m = 0; m < 4; ++m) {
        int r = m * 8 + sr;
        aR[m] = *(const floatx4*)&ain[(size_t)(row0 + r) * FEAT + IT0 * 32 + sk4];
        bR[m] = *(const floatx4*)&Wo[(size_t)(IT0 * 32 + r) * FEAT + col0 + sk4];
    }
    for (int it = IT0; it < IT1; ++it) {
        __syncthreads();
#pragma unroll
        for (int m = 0; m < 4; ++m) {
            int r = m * 8 + sr;
            AsT[w][sk4 + 0][r] = aR[m][0];
            AsT[w][sk4 + 1][r] = aR[m][1];
            AsT[w][sk4 + 2][r] = aR[m][2];
            AsT[w][sk4 + 3][r] = aR[m][3];
            *(floatx4*)&Bs[w][r][sk4] = bR[m];
        }
        __syncthreads();
        if (it + 1 < IT1) {
            int k0n = (it + 1) * 32;
#pragma unroll
            for (int m = 0; m < 4; ++m) {
                int r = m * 8 + sr;
                aR[m] = *(const floatx4*)&ain[(size_t)(row0 + r) * FEAT + k0n + sk4];
                bR[m] = *(const floatx4*)&Wo[(size_t)(k0n + r) * FEAT + col0 + sk4];
            }
        }
#pragma unroll
        for (int kk = 0; kk < 32; ++kk) {
            floatx4 a = *(const floatx4*)&AsT[w][kk][ty * 4];
            floatx4 b = *(const floatx4*)&Bs[w][kk][tx * 4];
#pragma unroll
            for (int i = 0; i < 4; ++i) acc[i] += a[i] * b;
        }
    }
    if (w == 1) {
#pragma unroll
        for (int i = 0; i < 4; ++i)
            *(floatx4*)&comb[ty * 4 + i][tx * 4] = acc[i];
    }
    __syncthreads();
    if (w == 0) {
#pragma unroll
        for (int i = 0; i < 4; ++i) {
            int row = row0 + ty * 4 + i;
            int c0 = col0 + tx * 4;
            floatx4 p = *(const floatx4*)&comb[ty * 4 + i][tx * 4];
            floatx4 a = acc[i] + p;
            floatx4 res = *(const floatx4*)&resid[(size_t)row * FEAT + c0];
            floatx4 o;
#pragma unroll
            for (int j = 0; j < 4; ++j) o[j] = res[j] + tanhf(a[j]);
            *(floatx4*)&xout[(size_t)row * FEAT + c0] = o;
            if (writeE) *(floatx4*)&ebufW[(size_t)row * INDP + c0] = o;
        }
    }
}

__global__ __launch_bounds__(256)
void attn(const float* __restrict__ q, const float* __restrict__ k,
          const float* __restrict__ v, float* __restrict__ ao) {
    __shared__ float qs[TT][DH], ks[TT][DH], vs[TT][DH];
    __shared__ float sc[TT][TT + 1];
    int bh = blockIdx.x;
    int b = bh >> 2, h = bh & 3;
    int tid = threadIdx.x;
    for (int i = tid; i < TT * DH; i += 256) {
        int r = i / DH, d = i - r * DH;
        size_t base = (size_t)(b * TT + r) * FEAT + h * DH + d;
        qs[r][d] = q[base]; ks[r][d] = k[base]; vs[r][d] = v[base];
    }
    __syncthreads();
    const float scale = 0.11180339887498949f;   // 1/sqrt(80)
    for (int idx = tid; idx < TT * TT; idx += 256) {
        int i = idx >> 6, j = idx & 63;
        float s = 0.f;
        for (int d = 0; d < DH; ++d) s += qs[i][d] * ks[j][d];
        sc[i][j] = s * scale;
    }
    __syncthreads();
    if (tid < TT) {
        int i = tid;
        if (i == 0) {
            for (int j = 0; j < TT; ++j) sc[0][j] = 0.0f;
        } else {
            float m = -1e30f;
            for (int j = 0; j < i; ++j) m = fmaxf(m, sc[i][j]);
            float sum = 0.f;
            for (int j = 0; j < i; ++j) { float p = __expf(sc[i][j] - m); sc[i][j] = p; sum += p; }
            float inv = 1.0f / sum;
            for (int j = 0; j < i; ++j) sc[i][j] *= inv;
            for (int j = i; j < TT; ++j) sc[i][j] = 0.0f;
        }
    }
    __syncthreads();
    for (int idx = tid; idx < TT * DH; idx += 256) {
        int i = idx / DH, d = idx - i * DH;
        float s = 0.f;
        for (int j = 0; j < TT; ++j) s += sc[i][j] * vs[j][d];
        ao[(size_t)(b * TT + i) * FEAT + h * DH + d] = s;
    }
}

__global__ __launch_bounds__(128)
void score_k(const float* __restrict__ x, const float* __restrict__ W1,
             const float* __restrict__ b1, const float* __restrict__ W2,
             const float* __restrict__ b2, float* __restrict__ lam_out,
             float* __restrict__ loss_out) {
    __shared__ float xr[FEAT];
    __shared__ float red[2];
    int e = blockIdx.x;
    int tid = threadIdx.x;
    for (int f = tid; f < FEAT; f += 128) xr[f] = x[(size_t)e * FEAT + f];
    __syncthreads();
    int d = tid;
    float acc = b1[d];
    for (int kk = 0; kk < FEAT; ++kk) acc += xr[kk] * W1[kk * DD + d];
    acc = fmaxf(acc, 0.0f) * W2[d];
    for (int off = 32; off; off >>= 1) acc += __shfl_down(acc, off, 64);
    if ((tid & 63) == 0) red[tid >> 6] = acc;
    __syncthreads();
    if (tid == 0) {
        float s = red[0] + red[1] + b2[0];
        float lam = fmaxf(s, 0.0f) + log1pf(expf(-fabsf(s)));   // softplus
        lam_out[e] = lam;
        atomicAdd(loss_out, -logf(lam + 1e-8f) * (1.0f / 2048.0f));
    }
}

// ---------------- launch ----------------
extern "C" void kernel_launch(void* const* d_in, const int* in_sizes, int n_in,
                              void* d_out, int out_size, void* d_ws, size_t ws_size,
                              hipStream_t stream) {
    const int*   seq_s = (const int*)d_in[0];
    const int*   seq_o = (const int*)d_in[1];
    const int*   seq_r = (const int*)d_in[2];
    const float* seq_t = (const float*)d_in[3];
    const float* mem0  = (const float*)d_in[4];
    const float* lt0   = (const float*)d_in[5];
    const float* rel   = (const float*)d_in[6];
    const float* W_hidden = (const float*)d_in[7];
    const float* W_hh  = (const float*)d_in[8];
    const float* W_st  = (const float*)d_in[9];
    const float* W_ot  = (const float*)d_in[10];
    const float* Wq    = (const float*)d_in[11];
    const float* Wk    = (const float*)d_in[12];
    const float* Wv    = (const float*)d_in[13];
    const float* Wo    = (const float*)d_in[14];
    const float* sW1   = (const float*)d_in[15];
    const float* sb1   = (const float*)d_in[16];
    const float* sW2   = (const float*)d_in[17];
    const float* sb2   = (const float*)d_in[18];

    float* out      = (float*)d_out;
    float* out_lam  = out + 1;
    float* out_mem  = out + 2049;
    float* out_lt   = out + 2049 + (size_t)NE * DD;

    float* ws = (float*)d_ws;
    float* evt   = ws;                         // 655360
    float* xbuf  = ws + 655360;                // 655360
    float* ebuf  = ws + 1310720;               // 2048*512 = 1048576
    float* qbuf  = ws + 2359296;               // 655360
    float* kbuf  = ws + 3014656;               // 655360
    float* vbuf  = ws + 3670016;               // 655360
    float* aobuf = ws + 4325376;               // 655360
    float* slotDt   = ws + 4980736;            // 4096
    int*   slotPrev = (int*)(ws + 4984832);    // 4096
    int*   slotWin  = (int*)(ws + 4988928);    // 4096
    int*   fixList  = (int*)(ws + 4993024);    // 2048
    int*   fixState = (int*)(ws + 4995072);    // 2048
    int*   evFixIdx = (int*)(ws + 4997120);    // 2048
    int*   fixCnt   = (int*)(ws + 4999168);    // 1

    hipMemsetAsync(fixCnt, 0, sizeof(int), stream);
    hipMemsetAsync(out, 0, sizeof(float), stream);
    hipMemsetAsync(ebuf, 0, (size_t)NEV * INDP * sizeof(float), stream);   // zero K-pad cols

    copy_init<<<2048, 256, 0, stream>>>(mem0, lt0, out_mem, out_lt);

    slot_analyze<<<NSLOT / 4, 256, 0, stream>>>(seq_s, seq_o, seq_t, lt0,
                                                slotDt, slotPrev, slotWin);
    fixlist_build<<<NEV / 256, 256, 0, stream>>>(slotPrev, fixList, fixState,
                                                 evFixIdx, fixCnt);
    event_compute<<<NEV / 8, 256, 0, stream>>>(seq_s, seq_o, seq_r, seq_t, mem0, rel,
                                               W_hidden, W_hh, W_st, W_ot, slotDt,
                                               evt, ebuf);
    for (int r = 0; r < 4; ++r)
        fix_round<<<64, 256, 0, stream>>>(r, seq_s, seq_o, mem0, W_hidden, W_hh,
                                          W_st, W_ot, slotDt, slotPrev,
                                          fixList, fixState, evFixIdx, fixCnt, evt, ebuf);
    scatter_win<<<512, 256, 0, stream>>>(seq_s, seq_o, seq_t, slotWin, evt, out_mem, out_lt);

    for (int l = 0; l < 2; ++l) {
        const float* src = l ? xbuf : evt;     // residual input
        proj<<<dim3(64, 10, 3), 128, 0, stream>>>(ebuf,
                                                  Wq + (size_t)l * IND * FEAT,
                                                  Wk + (size_t)l * IND * FEAT,
                                                  Wv + (size_t)l * IND * FEAT,
                                                  qbuf, kbuf, vbuf);
        attn<<<128, 256, 0, stream>>>(qbuf, kbuf, vbuf, aobuf);
        outproj<<<dim3(64, 10), 128, 0, stream>>>(aobuf, Wo + (size_t)l * FEAT * FEAT,
                                                  src, xbuf, ebuf, (l == 0) ? 1 : 0);
    }
    score_k<<<NEV, 128, 0, stream>>>(xbuf, sW1, sb1, sW2, sb2, out_lam, out);
}

// Round 9
// 505.562 us; speedup vs baseline: 1.1104x; 1.1104x over previous
//
#include <hip/hip_runtime.h>

// ---------------- problem dims ----------------
#define NE   200000
#define DC   64
#define DL   256
#define DD   128
#define FEAT 320          // 2*DD + DC
#define IND  449          // FEAT + DD + 1
#define INDP 512          // ebuf padded row stride (449 -> 512, pad zero-filled)
#define DH   80
#define BB   32
#define TT   64
#define NEV  2048         // BB*TT
#define NSLOT 4096

typedef __attribute__((ext_vector_type(4))) float  floatx4;
typedef __attribute__((ext_vector_type(4), aligned(4))) float floatx4u;   // dword-aligned vec4

__device__ __forceinline__ float sigmoidf_(float x) { return 1.0f / (1.0f + __expf(-x)); }

// ---------------- K0: output-state init copy (mem0 -> out_mem, lt0 -> out_lt) ----------
// At the mixed-stream copy floor (~60us across 4 structural variants); keep as-is.
__global__ __launch_bounds__(256)
void copy_init(const float* __restrict__ mem0, const float* __restrict__ lt0,
               float* __restrict__ out_mem, float* __restrict__ out_lt) {
    const size_t NM = (size_t)NE * DD;          // 25,600,000
    const size_t NL = (size_t)NE;               // 200,000
    size_t gid = (size_t)blockIdx.x * 256 + threadIdx.x;
    size_t stride = (size_t)gridDim.x * 256;
    if (gid == 0) {
        out_mem[0] = mem0[0]; out_mem[1] = mem0[1]; out_mem[2] = mem0[2];
        out_mem[NM - 1] = mem0[NM - 1];
        out_lt[0] = lt0[0]; out_lt[1] = lt0[1]; out_lt[2] = lt0[2];
        out_lt[NL - 1] = lt0[NL - 1];
    }
    const size_t nm4 = (NM - 4) / 4;            // vec4 stores over [3, NM-1)
    float* __restrict__ dm = out_mem + 3;       // 16B-aligned
    size_t i = gid;
    for (; i + 3 * stride < nm4; i += 4 * stride) {
        size_t i0 = i, i1 = i + stride, i2 = i + 2 * stride, i3 = i + 3 * stride;
        floatx4 lo0 = __builtin_nontemporal_load((const floatx4*)&mem0[i0 * 4]);
        floatx4 hi0 = __builtin_nontemporal_load((const floatx4*)&mem0[i0 * 4 + 4]);
        floatx4 lo1 = __builtin_nontemporal_load((const floatx4*)&mem0[i1 * 4]);
        floatx4 hi1 = __builtin_nontemporal_load((const floatx4*)&mem0[i1 * 4 + 4]);
        floatx4 lo2 = __builtin_nontemporal_load((const floatx4*)&mem0[i2 * 4]);
        floatx4 hi2 = __builtin_nontemporal_load((const floatx4*)&mem0[i2 * 4 + 4]);
        floatx4 lo3 = __builtin_nontemporal_load((const floatx4*)&mem0[i3 * 4]);
        floatx4 hi3 = __builtin_nontemporal_load((const floatx4*)&mem0[i3 * 4 + 4]);
        floatx4 o0 = {lo0[3], hi0[0], hi0[1], hi0[2]};
        floatx4 o1 = {lo1[3], hi1[0], hi1[1], hi1[2]};
        floatx4 o2 = {lo2[3], hi2[0], hi2[1], hi2[2]};
        floatx4 o3 = {lo3[3], hi3[0], hi3[1], hi3[2]};
        __builtin_nontemporal_store(o0, (floatx4*)&dm[i0 * 4]);
        __builtin_nontemporal_store(o1, (floatx4*)&dm[i1 * 4]);
        __builtin_nontemporal_store(o2, (floatx4*)&dm[i2 * 4]);
        __builtin_nontemporal_store(o3, (floatx4*)&dm[i3 * 4]);
    }
    for (; i < nm4; i += stride) {
        floatx4 lo = __builtin_nontemporal_load((const floatx4*)&mem0[i * 4]);
        floatx4 hi = __builtin_nontemporal_load((const floatx4*)&mem0[i * 4 + 4]);
        floatx4 o = {lo[3], hi[0], hi[1], hi[2]};
        __builtin_nontemporal_store(o, (floatx4*)&dm[i * 4]);
    }
    const size_t nl4 = (NL - 4) / 4;
    float* __restrict__ dl = out_lt + 3;        // 16B-aligned
    for (size_t j = gid; j < nl4; j += stride) {
        floatx4 lo = __builtin_nontemporal_load((const floatx4*)&lt0[j * 4]);
        floatx4 hi = __builtin_nontemporal_load((const floatx4*)&lt0[j * 4 + 4]);
        floatx4 o = {lo[3], hi[0], hi[1], hi[2]};
        __builtin_nontemporal_store(o, (floatx4*)&dl[j * 4]);
    }
}

// ---------------- K1: slot analysis (prev-toucher, dt, winner) ----------------
__global__ __launch_bounds__(256)
void slot_analyze(const int* __restrict__ seq_s, const int* __restrict__ seq_o,
                  const float* __restrict__ seq_time, const float* __restrict__ lt0,
                  float* __restrict__ slotDt, int* __restrict__ slotPrev,
                  int* __restrict__ slotWin) {
    __shared__ int entL[NSLOT];
    int tid = threadIdx.x;
    for (int j = tid; j < NSLOT; j += 256) {
        int b = j & 31, side = (j >> 5) & 1, t = j >> 6;
        entL[j] = (side ? seq_o : seq_s)[b * TT + t];
    }
    __syncthreads();
    int wave = tid >> 6, lane = tid & 63;
    int slot = blockIdx.x * 4 + wave;
    int t = slot >> 6;
    int myent = entL[slot];
    int win = 1, best = -1;
#pragma unroll 8
    for (int jj = 0; jj < NSLOT / 64; ++jj) {
        int j = jj * 64 + lane;
        if (entL[j] == myent) {
            if (j > slot) win = 0;
            else if ((j >> 6) < t && j > best) best = j;   // keeps max key among prior steps
        }
    }
#pragma unroll
    for (int off = 32; off; off >>= 1) {
        int ob = __shfl_xor(best, off, 64);
        best = best > ob ? best : ob;
    }
    win = __all(win);
    if (lane == 0) {
        int b = slot & 31;
        float tv = seq_time[b * TT + t];
        float pt = (best >= 0) ? seq_time[(best & 31) * TT + (best >> 6)] : lt0[myent];
        slotDt[slot]   = tv - pt;
        slotPrev[slot] = best;
        slotWin[slot]  = win;
    }
}

// ---------------- K1b: build fix list ----------------
__global__ __launch_bounds__(256)
void fixlist_build(const int* __restrict__ slotPrev, int* __restrict__ fixList,
                   int* __restrict__ fixState, int* __restrict__ evFixIdx,
                   int* __restrict__ fixCnt) {
    int e = blockIdx.x * 256 + threadIdx.x;   // 2048 events
    int b = e >> 6, t = e & 63;
    int c = (slotPrev[t * 64 + b] >= 0) | (slotPrev[t * 64 + 32 + b] >= 0);
    int idx = -1;
    if (c) { idx = atomicAdd(fixCnt, 1); fixList[idx] = e; fixState[idx] = -1; }
    evFixIdx[e] = idx;
}

// ---------------- K2: all-events parallel RNN compute (fp32) ----------------
__global__ __launch_bounds__(256)
void event_compute(const int* __restrict__ seq_s, const int* __restrict__ seq_o,
                   const int* __restrict__ seq_r, const float* __restrict__ seq_time,
                   const float* __restrict__ mem0, const float* __restrict__ rel,
                   const float* __restrict__ W_hidden, const float* __restrict__ W_hh,
                   const float* __restrict__ W_st, const float* __restrict__ W_ot,
                   const float* __restrict__ slotDt,
                   float* __restrict__ evt, float* __restrict__ ebuf) {
    __shared__ float xc[8][FEAT];
    __shared__ float hs[8][DL];
    __shared__ int   sSi[8], sOi[8], sRi[8];
    __shared__ float sDs[8], sDo[8], sTv[8];
    int tid = threadIdx.x;
    int e0 = blockIdx.x * 8;
    if (tid < 8) {
        int e = e0 + tid;
        sSi[tid] = seq_s[e]; sOi[tid] = seq_o[e]; sRi[tid] = seq_r[e];
        int b = e >> 6, t = e & 63;
        sDs[tid] = slotDt[t * 64 + b];
        sDo[tid] = slotDt[t * 64 + 32 + b];
        sTv[tid] = seq_time[e];
    }
    __syncthreads();
    for (int i = tid; i < 8 * FEAT; i += 256) {
        int r = i / FEAT, k = i - r * FEAT;
        float v;
        if (k < DD)            v = mem0[(size_t)sSi[r] * DD + k];
        else if (k < 2 * DD)   v = mem0[(size_t)sOi[r] * DD + (k - DD)];
        else                   v = rel[(size_t)sRi[r] * DC + (k - 2 * DD)];
        xc[r][k] = v;
    }
    __syncthreads();
    {   // z = xc @ W_hidden ; h = sigmoid(z)
        int j = tid;
        float acc[8] = {0.f,0.f,0.f,0.f,0.f,0.f,0.f,0.f};
        for (int k = 0; k < FEAT; ++k) {
            float w = W_hidden[(size_t)k * DL + j];
#pragma unroll
            for (int r = 0; r < 8; ++r) acc[r] += xc[r][k] * w;
        }
#pragma unroll
        for (int r = 0; r < 8; ++r) hs[r][j] = sigmoidf_(acc[r]);
    }
    __syncthreads();
    {   // hh = h @ W_hh ; ns/no = sigmoid(dt*W + hh)
        int d = tid & 127, grp = tid >> 7;
        float acc[4] = {0.f,0.f,0.f,0.f};
        for (int l = 0; l < DL; ++l) {
            float w = W_hh[(size_t)l * DD + d];
#pragma unroll
            for (int rr = 0; rr < 4; ++rr) acc[rr] += hs[grp * 4 + rr][l] * w;
        }
        float wst = W_st[d], wot = W_ot[d];
#pragma unroll
        for (int rr = 0; rr < 4; ++rr) {
            int r = grp * 4 + rr;
            int e = e0 + r;
            float ns  = sigmoidf_(sDs[r] * wst + acc[rr]);
            float no_ = sigmoidf_(sDo[r] * wot + acc[rr]);
            evt[(size_t)e * FEAT + d]      = ns;
            evt[(size_t)e * FEAT + DD + d] = no_;
            ebuf[(size_t)e * INDP + d]      = ns;
            ebuf[(size_t)e * INDP + DD + d] = no_;
        }
    }
    for (int i = tid; i < 8 * DC; i += 256) {
        int r = i >> 6, c = i & 63;
        float v = xc[r][2 * DD + c];
        int e = e0 + r;
        evt[(size_t)e * FEAT + 2 * DD + c] = v;
        ebuf[(size_t)e * INDP + 2 * DD + c] = v;
    }
    for (int i = tid; i < 8 * DD; i += 256) {
        int r = i >> 7, d = i & 127;
        float denom = __powf(1.0e4f, (float)d);     // inf for d>=10 -> 1/inf = 0 (matches ref)
        float v = sinf(sTv[r] * (1.0f / denom));
        int e = e0 + r;
        ebuf[(size_t)e * INDP + FEAT + d] = v;
    }
    if (tid < 8) ebuf[(size_t)(e0 + tid) * INDP + FEAT + DD] = 1.0f;
}

// ---------------- K3: fix rounds ----------------
__global__ __launch_bounds__(256)
void fix_round(int round,
               const int* __restrict__ seq_s, const int* __restrict__ seq_o,
               const float* __restrict__ mem0, const float* __restrict__ W_hidden,
               const float* __restrict__ W_hh, const float* __restrict__ W_st,
               const float* __restrict__ W_ot, const float* __restrict__ slotDt,
               const int* __restrict__ slotPrev, const int* __restrict__ fixList,
               int* __restrict__ fixState, const int* __restrict__ evFixIdx,
               const int* __restrict__ fixCnt,
               float* __restrict__ evt, float* __restrict__ ebuf) {
    __shared__ float xc[FEAT];
    __shared__ float hsv[DL];
    __shared__ float hp[2][DD];
    __shared__ int sGo, sPs, sPo, sE;
    int tid = threadIdx.x;
    int n = *fixCnt;
    for (int f = blockIdx.x; f < n; f += gridDim.x) {
        if (tid == 0) {
            int go = 0, ps = 0, po = 0, e = 0;
            if (fixState[f] == -1) {
                e = fixList[f];
                int b = e >> 6, t = e & 63;
                ps = slotPrev[t * 64 + b];
                po = slotPrev[t * 64 + 32 + b];
                go = 1;
                if (ps >= 0) {
                    int pe = (ps & 31) * 64 + (ps >> 6);
                    int fi = evFixIdx[pe];
                    if (fi >= 0) { int st = fixState[fi]; if (st < 0 || st >= round) go = 0; }
                }
                if (po >= 0) {
                    int pe = (po & 31) * 64 + (po >> 6);
                    int fi = evFixIdx[pe];
                    if (fi >= 0) { int st = fixState[fi]; if (st < 0 || st >= round) go = 0; }
                }
            }
            sGo = go; sPs = ps; sPo = po; sE = e;
        }
        __syncthreads();
        int go = sGo, ps = sPs, po = sPo, e = sE;
        __syncthreads();
        if (!go) continue;
        int b = e >> 6, t = e & 63;
        for (int i = tid; i < FEAT; i += 256) {
            float v;
            if (i < DD) {
                v = (ps >= 0) ? evt[(size_t)((ps & 31) * 64 + (ps >> 6)) * FEAT + ((ps >> 5) & 1) * DD + i]
                              : mem0[(size_t)seq_s[e] * DD + i];
            } else if (i < 2 * DD) {
                int k = i - DD;
                v = (po >= 0) ? evt[(size_t)((po & 31) * 64 + (po >> 6)) * FEAT + ((po >> 5) & 1) * DD + k]
                              : mem0[(size_t)seq_o[e] * DD + k];
            } else {
                v = evt[(size_t)e * FEAT + i];
            }
            xc[i] = v;
        }
        __syncthreads();
        {
            float a0 = 0.f, a1 = 0.f, a2 = 0.f, a3 = 0.f;
            for (int k = 0; k < FEAT; k += 4) {
                a0 += xc[k]     * W_hidden[(size_t)k * DL + tid];
                a1 += xc[k + 1] * W_hidden[(size_t)(k + 1) * DL + tid];
                a2 += xc[k + 2] * W_hidden[(size_t)(k + 2) * DL + tid];
                a3 += xc[k + 3] * W_hidden[(size_t)(k + 3) * DL + tid];
            }
            hsv[tid] = sigmoidf_((a0 + a1) + (a2 + a3));
        }
        __syncthreads();
        {
            int d = tid & 127, g = tid >> 7;
            float a0 = 0.f, a1 = 0.f;
            int l0 = g * 128;
            for (int l = 0; l < 128; l += 2) {
                a0 += hsv[l0 + l]     * W_hh[(size_t)(l0 + l) * DD + d];
                a1 += hsv[l0 + l + 1] * W_hh[(size_t)(l0 + l + 1) * DD + d];
            }
            hp[g][d] = a0 + a1;
        }
        __syncthreads();
        if (tid < DD) {
            float hh = hp[0][tid] + hp[1][tid];
            float ns  = sigmoidf_(slotDt[t * 64 + b]      * W_st[tid] + hh);
            float no_ = sigmoidf_(slotDt[t * 64 + 32 + b] * W_ot[tid] + hh);
            evt[(size_t)e * FEAT + tid]      = ns;
            evt[(size_t)e * FEAT + DD + tid] = no_;
            ebuf[(size_t)e * INDP + tid]      = ns;
            ebuf[(size_t)e * INDP + DD + tid] = no_;
        }
        __syncthreads();
        __threadfence();
        if (tid == 0) fixState[f] = round;
        __syncthreads();
    }
}

// ---------------- K4: winner scatter to out_mem / out_lt ----------------
__global__ __launch_bounds__(256)
void scatter_win(const int* __restrict__ seq_s, const int* __restrict__ seq_o,
                 const float* __restrict__ seq_time, const int* __restrict__ slotWin,
                 const float* __restrict__ evt, float* __restrict__ out_mem,
                 float* __restrict__ out_lt) {
    int gid = blockIdx.x * 256 + threadIdx.x;   // 131072 = 4096 slots * 32
    int slot = gid >> 5, c = gid & 31;
    if (!slotWin[slot]) return;
    int b = slot & 31, side = (slot >> 5) & 1, t = slot >> 6;
    int e = b * TT + t;
    int ent = (side ? seq_o : seq_s)[e];
    floatx4 v = *(const floatx4*)&evt[(size_t)e * FEAT + side * DD + c * 4];
    *(floatx4u*)&out_mem[(size_t)ent * DD + c * 4] = v;
    if (c == 0) out_lt[ent] = seq_time[e];
}

// ---------------- phase 2: split-K latency-optimized GEMMs ----------------
// proj: C[2048][320] = A[2048][512(INDP)] @ W[449][320] for z in {q,k,v}.
__global__ __launch_bounds__(128)
void proj(const float* __restrict__ ebuf, const float* __restrict__ Wq,
          const float* __restrict__ Wk, const float* __restrict__ Wv,
          float* __restrict__ q, float* __restrict__ k, float* __restrict__ v) {
    __shared__ float AsT[2][32][33];   // [wave][kk][r]
    __shared__ float Bs[2][32][36];    // [wave][kk][c]
    __shared__ float comb[32][36];
    const float* W = (blockIdx.z == 0) ? Wq : (blockIdx.z == 1) ? Wk : Wv;
    float* out = (blockIdx.z == 0) ? q : (blockIdx.z == 1) ? k : v;
    int tid = threadIdx.x;
    int w = tid >> 6, lane = tid & 63;
    int row0 = blockIdx.x * 32, col0 = blockIdx.y * 32;
    int tx = lane & 7, ty = lane >> 3;
    const int sr = lane >> 3, sk4 = (lane & 7) * 4;
    const int IT0 = w * 8, IT1 = IT0 + 8;       // 16 iters total (K=512 padded)
    floatx4 aR[4], bR[4], acc[4];
#pragma unroll
    for (int i = 0; i < 4; ++i) acc[i] = (floatx4){0.f, 0.f, 0.f, 0.f};
#pragma unroll
    for (int m = 0; m < 4; ++m) {
        int r = m * 8 + sr;
        int kg = IT0 * 32 + r;
        aR[m] = *(const floatx4*)&ebuf[(size_t)(row0 + r) * INDP + IT0 * 32 + sk4];
        bR[m] = (kg < IND) ? *(const floatx4*)&W[(size_t)kg * FEAT + col0 + sk4]
                           : (floatx4){0.f, 0.f, 0.f, 0.f};
    }
    for (int it = IT0; it < IT1; ++it) {
        __syncthreads();
#pragma unroll
        for (int m = 0; m < 4; ++m) {
            int r = m * 8 + sr;
            AsT[w][sk4 + 0][r] = aR[m][0];
            AsT[w][sk4 + 1][r] = aR[m][1];
            AsT[w][sk4 + 2][r] = aR[m][2];
            AsT[w][sk4 + 3][r] = aR[m][3];
            *(floatx4*)&Bs[w][r][sk4] = bR[m];
        }
        __syncthreads();
        if (it + 1 < IT1) {                      // prefetch next tile (overlaps compute)
            int k0n = (it + 1) * 32;
#pragma unroll
            for (int m = 0; m < 4; ++m) {
                int r = m * 8 + sr;
                int kg = k0n + r;
                aR[m] = *(const floatx4*)&ebuf[(size_t)(row0 + r) * INDP + k0n + sk4];
                bR[m] = (kg < IND) ? *(const floatx4*)&W[(size_t)kg * FEAT + col0 + sk4]
                                   : (floatx4){0.f, 0.f, 0.f, 0.f};
            }
        }
#pragma unroll
        for (int kk = 0; kk < 32; ++kk) {
            floatx4 a = *(const floatx4*)&AsT[w][kk][ty * 4];
            floatx4 b = *(const floatx4*)&Bs[w][kk][tx * 4];
#pragma unroll
            for (int i = 0; i < 4; ++i) acc[i] += a[i] * b;
        }
    }
    if (w == 1) {
#pragma unroll
        for (int i = 0; i < 4; ++i)
            *(floatx4*)&comb[ty * 4 + i][tx * 4] = acc[i];
    }
    __syncthreads();
    if (w == 0) {
#pragma unroll
        for (int i = 0; i < 4; ++i) {
            floatx4 p = *(const floatx4*)&comb[ty * 4 + i][tx * 4];
            floatx4 s = acc[i] + p;
            *(floatx4*)&out[(size_t)(row0 + ty * 4 + i) * FEAT + col0 + tx * 4] = s;
        }
    }
}

// outproj: acc = A[2048][320] @ Wo[320][320]; x = resid + tanh(acc); optional ebuf write.
__global__ __launch_bounds__(128)
void outproj(const float* __restrict__ ain, const float* __restrict__ Wo,
             const float* __restrict__ resid, float* __restrict__ xout,
             float* __restrict__ ebufW, int writeE) {
    __shared__ float AsT[2][32][33];
    __shared__ float Bs[2][32][36];
    __shared__ float comb[32][36];
    int tid = threadIdx.x;
    int w = tid >> 6, lane = tid & 63;
    int row0 = blockIdx.x * 32, col0 = blockIdx.y * 32;
    int tx = lane & 7, ty = lane >> 3;
    const int sr = lane >> 3, sk4 = (lane & 7) * 4;
    const int IT0 = w * 5, IT1 = IT0 + 5;       // 10 iters total (K=320 exact)
    floatx4 aR[4], bR[4], acc[4];
#pragma unroll
    for (int i = 0; i < 4; ++i) acc[i] = (floatx4){0.f, 0.f, 0.f, 0.f};
#pragma unroll
    for (int m = 0; m < 4; ++m) {
        int r = m * 8 + sr;
        aR[m] = *(const floatx4*)&ain[(size_t)(row0 + r) * FEAT + IT0 * 32 + sk4];
        bR[m] = *(const floatx4*)&Wo[(size_t)(IT0 * 32 + r) * FEAT + col0 + sk4];
    }
    for (int it = IT0; it < IT1; ++it) {
        __syncthreads();
#pragma unroll
        for (int m = 0; m < 4; ++m) {
            int r = m * 8 + sr;
            AsT[w][sk4 + 0][r] = aR[m][0];
            AsT[w][sk4 + 1][r] = aR[m][1];
            AsT[w][sk4 + 2][r] = aR[m][2];
            AsT[w][sk4 + 3][r] = aR[m][3];
            *(floatx4*)&Bs[w][r][sk4] = bR[m];
        }
        __syncthreads();
        if (it + 1 < IT1) {
            int k0n = (it + 1) * 32;
#pragma unroll
            for (int m = 0; m < 4; ++m) {
                int r = m * 8 + sr;
                aR[m] = *(const floatx4*)&ain[(size_t)(row0 + r) * FEAT + k0n + sk4];
                bR[m] = *(const floatx4*)&Wo[(size_t)(k0n + r) * FEAT + col0 + sk4];
            }
        }
#pragma unroll
        for (int kk = 0; kk < 32; ++kk) {
            floatx4 a = *(const floatx4*)&AsT[w][kk][ty * 4];
            floatx4 b = *(const floatx4*)&Bs[w][kk][tx * 4];
#pragma unroll
            for (int i = 0; i < 4; ++i) acc[i] += a[i] * b;
        }
    }
    if (w == 1) {
#pragma unroll
        for (int i = 0; i < 4; ++i)
            *(floatx4*)&comb[ty * 4 + i][tx * 4] = acc[i];
    }
    __syncthreads();
    if (w == 0) {
#pragma unroll
        for (int i = 0; i < 4; ++i) {
            int row = row0 + ty * 4 + i;
            int c0 = col0 + tx * 4;
            floatx4 p = *(const floatx4*)&comb[ty * 4 + i][tx * 4];
            floatx4 a = acc[i] + p;
            floatx4 res = *(const floatx4*)&resid[(size_t)row * FEAT + c0];
            floatx4 o;
#pragma unroll
            for (int j = 0; j < 4; ++j) o[j] = res[j] + tanhf(a[j]);
            *(floatx4*)&xout[(size_t)row * FEAT + c0] = o;
            if (writeE) *(floatx4*)&ebufW[(size_t)row * INDP + c0] = o;
        }
    }
}

// ---------------- attn: q-tiled, bank-conflict-free, wave-parallel softmax ----------
// Grid 512 = 32 b x 4 h x 4 q-tiles of 16. K/V LDS rows padded to 81 floats
// (81 mod 32 = 17, coprime -> 2 lanes/bank = free vs old stride-80 32-way conflict).
__global__ __launch_bounds__(256)
void attn(const float* __restrict__ q, const float* __restrict__ k,
          const float* __restrict__ v, float* __restrict__ ao) {
    __shared__ float qs[16][80];
    __shared__ float ks[TT][81];
    __shared__ float vs[TT][81];
    __shared__ float sc[16][65];
    int bh = blockIdx.x;
    int b = bh >> 4, h = (bh >> 2) & 3, qt = bh & 3;
    int tid = threadIdx.x;
    for (int i = tid; i < TT * DH; i += 256) {
        int r = i / DH, d = i - r * DH;
        size_t base = (size_t)(b * TT + r) * FEAT + h * DH + d;
        ks[r][d] = k[base];
        vs[r][d] = v[base];
    }
    for (int i = tid; i < 16 * DH; i += 256) {
        int r = i / DH, d = i - r * DH;
        qs[r][d] = q[(size_t)(b * TT + qt * 16 + r) * FEAT + h * DH + d];
    }
    __syncthreads();
    const float scale = 0.11180339887498949f;   // 1/sqrt(80)
    // QK^T: 16x64 scores; lane j consecutive, ks stride 81 -> conflict-free;
    // qs[i][*] is wave-uniform broadcast.
    for (int idx = tid; idx < 16 * 64; idx += 256) {
        int i = idx >> 6, j = idx & 63;
        float s = 0.f;
#pragma unroll 8
        for (int d = 0; d < DH; ++d) s += qs[i][d] * ks[j][d];
        sc[i][j] = s * scale;
    }
    __syncthreads();
    // softmax: 16-lane group per row, butterfly reduce (offsets <16 stay in group)
    {
        int r = tid >> 4, l = tid & 15;
        int qi = qt * 16 + r;
        float p0, p1, p2, p3;
        int j0 = l, j1 = l + 16, j2 = l + 32, j3 = l + 48;
        p0 = (j0 < qi) ? sc[r][j0] : -1e30f;
        p1 = (j1 < qi) ? sc[r][j1] : -1e30f;
        p2 = (j2 < qi) ? sc[r][j2] : -1e30f;
        p3 = (j3 < qi) ? sc[r][j3] : -1e30f;
        float m = fmaxf(fmaxf(p0, p1), fmaxf(p2, p3));
#pragma unroll
        for (int off = 8; off; off >>= 1) m = fmaxf(m, __shfl_xor(m, off, 64));
        p0 = (j0 < qi) ? __expf(p0 - m) : 0.f;
        p1 = (j1 < qi) ? __expf(p1 - m) : 0.f;
        p2 = (j2 < qi) ? __expf(p2 - m) : 0.f;
        p3 = (j3 < qi) ? __expf(p3 - m) : 0.f;
        float sum = (p0 + p1) + (p2 + p3);
#pragma unroll
        for (int off = 8; off; off >>= 1) sum += __shfl_xor(sum, off, 64);
        float inv = (qi > 0) ? 1.0f / sum : 0.f;
        sc[r][j0] = p0 * inv;
        sc[r][j1] = p1 * inv;
        sc[r][j2] = p2 * inv;
        sc[r][j3] = p3 * inv;
    }
    __syncthreads();
    // PV: 16x80 outputs; sc[i][j] broadcast, vs[j][d] d-consecutive
    for (int idx = tid; idx < 16 * DH; idx += 256) {
        int i = idx / DH, d = idx - i * DH;
        float s = 0.f;
#pragma unroll 8
        for (int j = 0; j < TT; ++j) s += sc[i][j] * vs[j][d];
        ao[(size_t)(b * TT + qt * 16 + i) * FEAT + h * DH + d] = s;
    }
}

__global__ __launch_bounds__(128)
void score_k(const float* __restrict__ x, const float* __restrict__ W1,
             const float* __restrict__ b1, const float* __restrict__ W2,
             const float* __restrict__ b2, float* __restrict__ lam_out,
             float* __restrict__ loss_out) {
    __shared__ float xr[FEAT];
    __shared__ float red[2];
    int e = blockIdx.x;
    int tid = threadIdx.x;
    for (int f = tid; f < FEAT; f += 128) xr[f] = x[(size_t)e * FEAT + f];
    __syncthreads();
    int d = tid;
    float acc = b1[d];
    for (int kk = 0; kk < FEAT; ++kk) acc += xr[kk] * W1[kk * DD + d];
    acc = fmaxf(acc, 0.0f) * W2[d];
    for (int off = 32; off; off >>= 1) acc += __shfl_down(acc, off, 64);
    if ((tid & 63) == 0) red[tid >> 6] = acc;
    __syncthreads();
    if (tid == 0) {
        float s = red[0] + red[1] + b2[0];
        float lam = fmaxf(s, 0.0f) + log1pf(expf(-fabsf(s)));   // softplus
        lam_out[e] = lam;
        atomicAdd(loss_out, -logf(lam + 1e-8f) * (1.0f / 2048.0f));
    }
}

// ---------------- launch ----------------
extern "C" void kernel_launch(void* const* d_in, const int* in_sizes, int n_in,
                              void* d_out, int out_size, void* d_ws, size_t ws_size,
                              hipStream_t stream) {
    const int*   seq_s = (const int*)d_in[0];
    const int*   seq_o = (const int*)d_in[1];
    const int*   seq_r = (const int*)d_in[2];
    const float* seq_t = (const float*)d_in[3];
    const float* mem0  = (const float*)d_in[4];
    const float* lt0   = (const float*)d_in[5];
    const float* rel   = (const float*)d_in[6];
    const float* W_hidden = (const float*)d_in[7];
    const float* W_hh  = (const float*)d_in[8];
    const float* W_st  = (const float*)d_in[9];
    const float* W_ot  = (const float*)d_in[10];
    const float* Wq    = (const float*)d_in[11];
    const float* Wk    = (const float*)d_in[12];
    const float* Wv    = (const float*)d_in[13];
    const float* Wo    = (const float*)d_in[14];
    const float* sW1   = (const float*)d_in[15];
    const float* sb1   = (const float*)d_in[16];
    const float* sW2   = (const float*)d_in[17];
    const float* sb2   = (const float*)d_in[18];

    float* out      = (float*)d_out;
    float* out_lam  = out + 1;
    float* out_mem  = out + 2049;
    float* out_lt   = out + 2049 + (size_t)NE * DD;

    float* ws = (float*)d_ws;
    float* evt   = ws;                         // 655360
    float* xbuf  = ws + 655360;                // 655360
    float* ebuf  = ws + 1310720;               // 2048*512 = 1048576
    float* qbuf  = ws + 2359296;               // 655360
    float* kbuf  = ws + 3014656;               // 655360
    float* vbuf  = ws + 3670016;               // 655360
    float* aobuf = ws + 4325376;               // 655360
    float* slotDt   = ws + 4980736;            // 4096
    int*   slotPrev = (int*)(ws + 4984832);    // 4096
    int*   slotWin  = (int*)(ws + 4988928);    // 4096
    int*   fixList  = (int*)(ws + 4993024);    // 2048
    int*   fixState = (int*)(ws + 4995072);    // 2048
    int*   evFixIdx = (int*)(ws + 4997120);    // 2048
    int*   fixCnt   = (int*)(ws + 4999168);    // 1

    hipMemsetAsync(fixCnt, 0, sizeof(int), stream);
    hipMemsetAsync(out, 0, sizeof(float), stream);
    hipMemsetAsync(ebuf, 0, (size_t)NEV * INDP * sizeof(float), stream);   // zero K-pad cols

    copy_init<<<2048, 256, 0, stream>>>(mem0, lt0, out_mem, out_lt);

    slot_analyze<<<NSLOT / 4, 256, 0, stream>>>(seq_s, seq_o, seq_t, lt0,
                                                slotDt, slotPrev, slotWin);
    fixlist_build<<<NEV / 256, 256, 0, stream>>>(slotPrev, fixList, fixState,
                                                 evFixIdx, fixCnt);
    event_compute<<<NEV / 8, 256, 0, stream>>>(seq_s, seq_o, seq_r, seq_t, mem0, rel,
                                               W_hidden, W_hh, W_st, W_ot, slotDt,
                                               evt, ebuf);
    for (int r = 0; r < 4; ++r)
        fix_round<<<64, 256, 0, stream>>>(r, seq_s, seq_o, mem0, W_hidden, W_hh,
                                          W_st, W_ot, slotDt, slotPrev,
                                          fixList, fixState, evFixIdx, fixCnt, evt, ebuf);
    scatter_win<<<512, 256, 0, stream>>>(seq_s, seq_o, seq_t, slotWin, evt, out_mem, out_lt);

    for (int l = 0; l < 2; ++l) {
        const float* src = l ? xbuf : evt;     // residual input
        proj<<<dim3(64, 10, 3), 128, 0, stream>>>(ebuf,
                                                  Wq + (size_t)l * IND * FEAT,
                                                  Wk + (size_t)l * IND * FEAT,
                                                  Wv + (size_t)l * IND * FEAT,
                                                  qbuf, kbuf, vbuf);
        attn<<<512, 256, 0, stream>>>(qbuf, kbuf, vbuf, aobuf);
        outproj<<<dim3(64, 10), 128, 0, stream>>>(aobuf, Wo + (size_t)l * FEAT * FEAT,
                                                  src, xbuf, ebuf, (l == 0) ? 1 : 0);
    }
    score_k<<<NEV, 128, 0, stream>>>(xbuf, sW1, sb1, sW2, sb2, out_lam, out);
}

// Round 10
// 494.548 us; speedup vs baseline: 1.1351x; 1.0223x over previous
//
#include <hip/hip_runtime.h>

// ---------------- problem dims ----------------
#define NE   200000
#define DC   64
#define DL   256
#define DD   128
#define FEAT 320          // 2*DD + DC
#define IND  449          // FEAT + DD + 1
#define INDP 512          // ebuf padded row stride (449 -> 512, pad zero-filled)
#define DH   80
#define BB   32
#define TT   64
#define NEV  2048         // BB*TT
#define NSLOT 4096

typedef __attribute__((ext_vector_type(4))) float  floatx4;
typedef __attribute__((ext_vector_type(4), aligned(4))) float floatx4u;   // dword-aligned vec4

__device__ __forceinline__ float sigmoidf_(float x) { return 1.0f / (1.0f + __expf(-x)); }

// ---------------- K0: output-state init copy (mem0 -> out_mem, lt0 -> out_lt) ----------
// At the mixed-stream copy floor (~60us across 4 structural variants); keep as-is.
__global__ __launch_bounds__(256)
void copy_init(const float* __restrict__ mem0, const float* __restrict__ lt0,
               float* __restrict__ out_mem, float* __restrict__ out_lt) {
    const size_t NM = (size_t)NE * DD;          // 25,600,000
    const size_t NL = (size_t)NE;               // 200,000
    size_t gid = (size_t)blockIdx.x * 256 + threadIdx.x;
    size_t stride = (size_t)gridDim.x * 256;
    if (gid == 0) {
        out_mem[0] = mem0[0]; out_mem[1] = mem0[1]; out_mem[2] = mem0[2];
        out_mem[NM - 1] = mem0[NM - 1];
        out_lt[0] = lt0[0]; out_lt[1] = lt0[1]; out_lt[2] = lt0[2];
        out_lt[NL - 1] = lt0[NL - 1];
    }
    const size_t nm4 = (NM - 4) / 4;            // vec4 stores over [3, NM-1)
    float* __restrict__ dm = out_mem + 3;       // 16B-aligned
    size_t i = gid;
    for (; i + 3 * stride < nm4; i += 4 * stride) {
        size_t i0 = i, i1 = i + stride, i2 = i + 2 * stride, i3 = i + 3 * stride;
        floatx4 lo0 = __builtin_nontemporal_load((const floatx4*)&mem0[i0 * 4]);
        floatx4 hi0 = __builtin_nontemporal_load((const floatx4*)&mem0[i0 * 4 + 4]);
        floatx4 lo1 = __builtin_nontemporal_load((const floatx4*)&mem0[i1 * 4]);
        floatx4 hi1 = __builtin_nontemporal_load((const floatx4*)&mem0[i1 * 4 + 4]);
        floatx4 lo2 = __builtin_nontemporal_load((const floatx4*)&mem0[i2 * 4]);
        floatx4 hi2 = __builtin_nontemporal_load((const floatx4*)&mem0[i2 * 4 + 4]);
        floatx4 lo3 = __builtin_nontemporal_load((const floatx4*)&mem0[i3 * 4]);
        floatx4 hi3 = __builtin_nontemporal_load((const floatx4*)&mem0[i3 * 4 + 4]);
        floatx4 o0 = {lo0[3], hi0[0], hi0[1], hi0[2]};
        floatx4 o1 = {lo1[3], hi1[0], hi1[1], hi1[2]};
        floatx4 o2 = {lo2[3], hi2[0], hi2[1], hi2[2]};
        floatx4 o3 = {lo3[3], hi3[0], hi3[1], hi3[2]};
        __builtin_nontemporal_store(o0, (floatx4*)&dm[i0 * 4]);
        __builtin_nontemporal_store(o1, (floatx4*)&dm[i1 * 4]);
        __builtin_nontemporal_store(o2, (floatx4*)&dm[i2 * 4]);
        __builtin_nontemporal_store(o3, (floatx4*)&dm[i3 * 4]);
    }
    for (; i < nm4; i += stride) {
        floatx4 lo = __builtin_nontemporal_load((const floatx4*)&mem0[i * 4]);
        floatx4 hi = __builtin_nontemporal_load((const floatx4*)&mem0[i * 4 + 4]);
        floatx4 o = {lo[3], hi[0], hi[1], hi[2]};
        __builtin_nontemporal_store(o, (floatx4*)&dm[i * 4]);
    }
    const size_t nl4 = (NL - 4) / 4;
    float* __restrict__ dl = out_lt + 3;        // 16B-aligned
    for (size_t j = gid; j < nl4; j += stride) {
        floatx4 lo = __builtin_nontemporal_load((const floatx4*)&lt0[j * 4]);
        floatx4 hi = __builtin_nontemporal_load((const floatx4*)&lt0[j * 4 + 4]);
        floatx4 o = {lo[3], hi[0], hi[1], hi[2]};
        __builtin_nontemporal_store(o, (floatx4*)&dl[j * 4]);
    }
}

// ---------------- K1: slot analysis (8 slots/block, 2 per wave) ----------------
__global__ __launch_bounds__(256)
void slot_analyze(const int* __restrict__ seq_s, const int* __restrict__ seq_o,
                  const float* __restrict__ seq_time, const float* __restrict__ lt0,
                  float* __restrict__ slotDt, int* __restrict__ slotPrev,
                  int* __restrict__ slotWin) {
    __shared__ int entL[NSLOT];
    int tid = threadIdx.x;
    for (int j = tid; j < NSLOT; j += 256) {
        int b = j & 31, side = (j >> 5) & 1, t = j >> 6;
        entL[j] = (side ? seq_o : seq_s)[b * TT + t];
    }
    __syncthreads();
    int wave = tid >> 6, lane = tid & 63;
    for (int s = 0; s < 2; ++s) {
        int slot = blockIdx.x * 8 + wave * 2 + s;
        int t = slot >> 6;
        int myent = entL[slot];
        int win = 1, best = -1;
#pragma unroll 8
        for (int jj = 0; jj < NSLOT / 64; ++jj) {
            int j = jj * 64 + lane;
            if (entL[j] == myent) {
                if (j > slot) win = 0;
                else if ((j >> 6) < t && j > best) best = j;   // max key among prior steps
            }
        }
#pragma unroll
        for (int off = 32; off; off >>= 1) {
            int ob = __shfl_xor(best, off, 64);
            best = best > ob ? best : ob;
        }
        win = __all(win);
        if (lane == 0) {
            int b = slot & 31;
            float tv = seq_time[b * TT + t];
            float pt = (best >= 0) ? seq_time[(best & 31) * TT + (best >> 6)] : lt0[myent];
            slotDt[slot]   = tv - pt;
            slotPrev[slot] = best;
            slotWin[slot]  = win;
        }
    }
}

// ---------------- K1b: build fix list ----------------
__global__ __launch_bounds__(256)
void fixlist_build(const int* __restrict__ slotPrev, int* __restrict__ fixList,
                   int* __restrict__ fixState, int* __restrict__ evFixIdx,
                   int* __restrict__ fixCnt) {
    int e = blockIdx.x * 256 + threadIdx.x;   // 2048 events
    int b = e >> 6, t = e & 63;
    int c = (slotPrev[t * 64 + b] >= 0) | (slotPrev[t * 64 + 32 + b] >= 0);
    int idx = -1;
    if (c) { idx = atomicAdd(fixCnt, 1); fixList[idx] = e; fixState[idx] = -1; }
    evFixIdx[e] = idx;
}

// ---------------- K2: all-events parallel RNN compute (fp32) ----------------
// 4 events/block (512 blocks, 8 waves/CU); vectorized b128 LDS reads in both GEMVs.
// Also zeroes ebuf pad cols 449..511 (replaces the 4MB memset launch).
__global__ __launch_bounds__(256)
void event_compute(const int* __restrict__ seq_s, const int* __restrict__ seq_o,
                   const int* __restrict__ seq_r, const float* __restrict__ seq_time,
                   const float* __restrict__ mem0, const float* __restrict__ rel,
                   const float* __restrict__ W_hidden, const float* __restrict__ W_hh,
                   const float* __restrict__ W_st, const float* __restrict__ W_ot,
                   const float* __restrict__ slotDt,
                   float* __restrict__ evt, float* __restrict__ ebuf) {
    __shared__ float xc[4][FEAT];
    __shared__ float hs[4][DL];
    __shared__ int   sSi[4], sOi[4], sRi[4];
    __shared__ float sDs[4], sDo[4], sTv[4];
    int tid = threadIdx.x;
    int e0 = blockIdx.x * 4;
    if (tid < 4) {
        int e = e0 + tid;
        sSi[tid] = seq_s[e]; sOi[tid] = seq_o[e]; sRi[tid] = seq_r[e];
        int b = e >> 6, t = e & 63;
        sDs[tid] = slotDt[t * 64 + b];
        sDo[tid] = slotDt[t * 64 + 32 + b];
        sTv[tid] = seq_time[e];
    }
    __syncthreads();
    for (int i = tid; i < 4 * FEAT; i += 256) {
        int r = i / FEAT, k = i - r * FEAT;
        float v;
        if (k < DD)            v = mem0[(size_t)sSi[r] * DD + k];
        else if (k < 2 * DD)   v = mem0[(size_t)sOi[r] * DD + (k - DD)];
        else                   v = rel[(size_t)sRi[r] * DC + (k - 2 * DD)];
        xc[r][k] = v;
    }
    __syncthreads();
    {   // z = xc @ W_hidden ; h = sigmoid(z)  (k ascending, order preserved)
        int j = tid;
        float acc[4] = {0.f, 0.f, 0.f, 0.f};
        for (int k0 = 0; k0 < FEAT; k0 += 4) {
            float w0 = W_hidden[(size_t)(k0 + 0) * DL + j];
            float w1 = W_hidden[(size_t)(k0 + 1) * DL + j];
            float w2 = W_hidden[(size_t)(k0 + 2) * DL + j];
            float w3 = W_hidden[(size_t)(k0 + 3) * DL + j];
#pragma unroll
            for (int r = 0; r < 4; ++r) {
                floatx4 xv = *(const floatx4*)&xc[r][k0];
                acc[r] += xv[0] * w0;
                acc[r] += xv[1] * w1;
                acc[r] += xv[2] * w2;
                acc[r] += xv[3] * w3;
            }
        }
#pragma unroll
        for (int r = 0; r < 4; ++r) hs[r][j] = sigmoidf_(acc[r]);
    }
    __syncthreads();
    {   // hh = h @ W_hh ; ns/no = sigmoid(dt*W + hh)
        int d = tid & 127, grp = tid >> 7;     // grp 0 -> events 0,1; grp 1 -> 2,3
        float acc[2] = {0.f, 0.f};
        for (int l0 = 0; l0 < DL; l0 += 4) {
            float w0 = W_hh[(size_t)(l0 + 0) * DD + d];
            float w1 = W_hh[(size_t)(l0 + 1) * DD + d];
            float w2 = W_hh[(size_t)(l0 + 2) * DD + d];
            float w3 = W_hh[(size_t)(l0 + 3) * DD + d];
#pragma unroll
            for (int rr = 0; rr < 2; ++rr) {
                floatx4 hv = *(const floatx4*)&hs[grp * 2 + rr][l0];
                acc[rr] += hv[0] * w0;
                acc[rr] += hv[1] * w1;
                acc[rr] += hv[2] * w2;
                acc[rr] += hv[3] * w3;
            }
        }
        float wst = W_st[d], wot = W_ot[d];
#pragma unroll
        for (int rr = 0; rr < 2; ++rr) {
            int r = grp * 2 + rr;
            int e = e0 + r;
            float ns  = sigmoidf_(sDs[r] * wst + acc[rr]);
            float no_ = sigmoidf_(sDo[r] * wot + acc[rr]);
            evt[(size_t)e * FEAT + d]      = ns;
            evt[(size_t)e * FEAT + DD + d] = no_;
            ebuf[(size_t)e * INDP + d]      = ns;
            ebuf[(size_t)e * INDP + DD + d] = no_;
        }
    }
    for (int i = tid; i < 4 * DC; i += 256) {
        int r = i >> 6, c = i & 63;
        float v = xc[r][2 * DD + c];
        int e = e0 + r;
        evt[(size_t)e * FEAT + 2 * DD + c] = v;
        ebuf[(size_t)e * INDP + 2 * DD + c] = v;
    }
    for (int i = tid; i < 4 * DD; i += 256) {
        int r = i >> 7, d = i & 127;
        float denom = __powf(1.0e4f, (float)d);     // inf for d>=10 -> 1/inf = 0 (matches ref)
        float v = sinf(sTv[r] * (1.0f / denom));
        int e = e0 + r;
        ebuf[(size_t)e * INDP + FEAT + d] = v;
    }
    // ones col (448) + zero pad cols (449..511): replaces the ebuf memset
    for (int i = tid; i < 4 * 64; i += 256) {
        int r = i >> 6, c = i & 63;
        ebuf[(size_t)(e0 + r) * INDP + (FEAT + DD) + c] = (c == 0) ? 1.0f : 0.0f;
    }
}

// ---------------- K3: fix rounds ----------------
__global__ __launch_bounds__(256)
void fix_round(int round,
               const int* __restrict__ seq_s, const int* __restrict__ seq_o,
               const float* __restrict__ mem0, const float* __restrict__ W_hidden,
               const float* __restrict__ W_hh, const float* __restrict__ W_st,
               const float* __restrict__ W_ot, const float* __restrict__ slotDt,
               const int* __restrict__ slotPrev, const int* __restrict__ fixList,
               int* __restrict__ fixState, const int* __restrict__ evFixIdx,
               const int* __restrict__ fixCnt,
               float* __restrict__ evt, float* __restrict__ ebuf) {
    __shared__ float xc[FEAT];
    __shared__ float hsv[DL];
    __shared__ float hp[2][DD];
    __shared__ int sGo, sPs, sPo, sE;
    int tid = threadIdx.x;
    int n = *fixCnt;
    for (int f = blockIdx.x; f < n; f += gridDim.x) {
        if (tid == 0) {
            int go = 0, ps = 0, po = 0, e = 0;
            if (fixState[f] == -1) {
                e = fixList[f];
                int b = e >> 6, t = e & 63;
                ps = slotPrev[t * 64 + b];
                po = slotPrev[t * 64 + 32 + b];
                go = 1;
                if (ps >= 0) {
                    int pe = (ps & 31) * 64 + (ps >> 6);
                    int fi = evFixIdx[pe];
                    if (fi >= 0) { int st = fixState[fi]; if (st < 0 || st >= round) go = 0; }
                }
                if (po >= 0) {
                    int pe = (po & 31) * 64 + (po >> 6);
                    int fi = evFixIdx[pe];
                    if (fi >= 0) { int st = fixState[fi]; if (st < 0 || st >= round) go = 0; }
                }
            }
            sGo = go; sPs = ps; sPo = po; sE = e;
        }
        __syncthreads();
        int go = sGo, ps = sPs, po = sPo, e = sE;
        __syncthreads();
        if (!go) continue;
        int b = e >> 6, t = e & 63;
        for (int i = tid; i < FEAT; i += 256) {
            float v;
            if (i < DD) {
                v = (ps >= 0) ? evt[(size_t)((ps & 31) * 64 + (ps >> 6)) * FEAT + ((ps >> 5) & 1) * DD + i]
                              : mem0[(size_t)seq_s[e] * DD + i];
            } else if (i < 2 * DD) {
                int k = i - DD;
                v = (po >= 0) ? evt[(size_t)((po & 31) * 64 + (po >> 6)) * FEAT + ((po >> 5) & 1) * DD + k]
                              : mem0[(size_t)seq_o[e] * DD + k];
            } else {
                v = evt[(size_t)e * FEAT + i];
            }
            xc[i] = v;
        }
        __syncthreads();
        {
            float a0 = 0.f, a1 = 0.f, a2 = 0.f, a3 = 0.f;
            for (int k = 0; k < FEAT; k += 4) {
                floatx4 xv = *(const floatx4*)&xc[k];
                a0 += xv[0] * W_hidden[(size_t)k * DL + tid];
                a1 += xv[1] * W_hidden[(size_t)(k + 1) * DL + tid];
                a2 += xv[2] * W_hidden[(size_t)(k + 2) * DL + tid];
                a3 += xv[3] * W_hidden[(size_t)(k + 3) * DL + tid];
            }
            hsv[tid] = sigmoidf_((a0 + a1) + (a2 + a3));
        }
        __syncthreads();
        {
            int d = tid & 127, g = tid >> 7;
            float a0 = 0.f, a1 = 0.f;
            int l0 = g * 128;
            for (int l = 0; l < 128; l += 2) {
                a0 += hsv[l0 + l]     * W_hh[(size_t)(l0 + l) * DD + d];
                a1 += hsv[l0 + l + 1] * W_hh[(size_t)(l0 + l + 1) * DD + d];
            }
            hp[g][d] = a0 + a1;
        }
        __syncthreads();
        if (tid < DD) {
            float hh = hp[0][tid] + hp[1][tid];
            float ns  = sigmoidf_(slotDt[t * 64 + b]      * W_st[tid] + hh);
            float no_ = sigmoidf_(slotDt[t * 64 + 32 + b] * W_ot[tid] + hh);
            evt[(size_t)e * FEAT + tid]      = ns;
            evt[(size_t)e * FEAT + DD + tid] = no_;
            ebuf[(size_t)e * INDP + tid]      = ns;
            ebuf[(size_t)e * INDP + DD + tid] = no_;
        }
        __syncthreads();
        __threadfence();
        if (tid == 0) fixState[f] = round;
        __syncthreads();
    }
}

// ---------------- K4: winner scatter to out_mem / out_lt ----------------
__global__ __launch_bounds__(256)
void scatter_win(const int* __restrict__ seq_s, const int* __restrict__ seq_o,
                 const float* __restrict__ seq_time, const int* __restrict__ slotWin,
                 const float* __restrict__ evt, float* __restrict__ out_mem,
                 float* __restrict__ out_lt) {
    int gid = blockIdx.x * 256 + threadIdx.x;   // 131072 = 4096 slots * 32
    int slot = gid >> 5, c = gid & 31;
    if (!slotWin[slot]) return;
    int b = slot & 31, side = (slot >> 5) & 1, t = slot >> 6;
    int e = b * TT + t;
    int ent = (side ? seq_o : seq_s)[e];
    floatx4 v = *(const floatx4*)&evt[(size_t)e * FEAT + side * DD + c * 4];
    *(floatx4u*)&out_mem[(size_t)ent * DD + c * 4] = v;
    if (c == 0) out_lt[ent] = seq_time[e];
}

// ---------------- phase 2: split-K latency-optimized GEMMs ----------------
// proj: C[2048][320] = A[2048][512(INDP)] @ W[449][320] for z in {q,k,v}.
__global__ __launch_bounds__(128)
void proj(const float* __restrict__ ebuf, const float* __restrict__ Wq,
          const float* __restrict__ Wk, const float* __restrict__ Wv,
          float* __restrict__ q, float* __restrict__ k, float* __restrict__ v) {
    __shared__ float AsT[2][32][33];   // [wave][kk][r]
    __shared__ float Bs[2][32][36];    // [wave][kk][c]
    __shared__ float comb[32][36];
    const float* W = (blockIdx.z == 0) ? Wq : (blockIdx.z == 1) ? Wk : Wv;
    float* out = (blockIdx.z == 0) ? q : (blockIdx.z == 1) ? k : v;
    int tid = threadIdx.x;
    int w = tid >> 6, lane = tid & 63;
    int row0 = blockIdx.x * 32, col0 = blockIdx.y * 32;
    int tx = lane & 7, ty = lane >> 3;
    const int sr = lane >> 3, sk4 = (lane & 7) * 4;
    const int IT0 = w * 8, IT1 = IT0 + 8;       // 16 iters total (K=512 padded)
    floatx4 aR[4], bR[4], acc[4];
#pragma unroll
    for (int i = 0; i < 4; ++i) acc[i] = (floatx4){0.f, 0.f, 0.f, 0.f};
#pragma unroll
    for (int m = 0; m < 4; ++m) {
        int r = m * 8 + sr;
        int kg = IT0 * 32 + r;
        aR[m] = *(const floatx4*)&ebuf[(size_t)(row0 + r) * INDP + IT0 * 32 + sk4];
        bR[m] = (kg < IND) ? *(const floatx4*)&W[(size_t)kg * FEAT + col0 + sk4]
                           : (floatx4){0.f, 0.f, 0.f, 0.f};
    }
    for (int it = IT0; it < IT1; ++it) {
        __syncthreads();
#pragma unroll
        for (int m = 0; m < 4; ++m) {
            int r = m * 8 + sr;
            AsT[w][sk4 + 0][r] = aR[m][0];
            AsT[w][sk4 + 1][r] = aR[m][1];
            AsT[w][sk4 + 2][r] = aR[m][2];
            AsT[w][sk4 + 3][r] = aR[m][3];
            *(floatx4*)&Bs[w][r][sk4] = bR[m];
        }
        __syncthreads();
        if (it + 1 < IT1) {                      // prefetch next tile (overlaps compute)
            int k0n = (it + 1) * 32;
#pragma unroll
            for (int m = 0; m < 4; ++m) {
                int r = m * 8 + sr;
                int kg = k0n + r;
                aR[m] = *(const floatx4*)&ebuf[(size_t)(row0 + r) * INDP + k0n + sk4];
                bR[m] = (kg < IND) ? *(const floatx4*)&W[(size_t)kg * FEAT + col0 + sk4]
                                   : (floatx4){0.f, 0.f, 0.f, 0.f};
            }
        }
#pragma unroll
        for (int kk = 0; kk < 32; ++kk) {
            floatx4 a = *(const floatx4*)&AsT[w][kk][ty * 4];
            floatx4 b = *(const floatx4*)&Bs[w][kk][tx * 4];
#pragma unroll
            for (int i = 0; i < 4; ++i) acc[i] += a[i] * b;
        }
    }
    if (w == 1) {
#pragma unroll
        for (int i = 0; i < 4; ++i)
            *(floatx4*)&comb[ty * 4 + i][tx * 4] = acc[i];
    }
    __syncthreads();
    if (w == 0) {
#pragma unroll
        for (int i = 0; i < 4; ++i) {
            floatx4 p = *(const floatx4*)&comb[ty * 4 + i][tx * 4];
            floatx4 s = acc[i] + p;
            *(floatx4*)&out[(size_t)(row0 + ty * 4 + i) * FEAT + col0 + tx * 4] = s;
        }
    }
}

// outproj: acc = A[2048][320] @ Wo[320][320]; x = resid + tanh(acc); optional ebuf write.
__global__ __launch_bounds__(128)
void outproj(const float* __restrict__ ain, const float* __restrict__ Wo,
             const float* __restrict__ resid, float* __restrict__ xout,
             float* __restrict__ ebufW, int writeE) {
    __shared__ float AsT[2][32][33];
    __shared__ float Bs[2][32][36];
    __shared__ float comb[32][36];
    int tid = threadIdx.x;
    int w = tid >> 6, lane = tid & 63;
    int row0 = blockIdx.x * 32, col0 = blockIdx.y * 32;
    int tx = lane & 7, ty = lane >> 3;
    const int sr = lane >> 3, sk4 = (lane & 7) * 4;
    const int IT0 = w * 5, IT1 = IT0 + 5;       // 10 iters total (K=320 exact)
    floatx4 aR[4], bR[4], acc[4];
#pragma unroll
    for (int i = 0; i < 4; ++i) acc[i] = (floatx4){0.f, 0.f, 0.f, 0.f};
#pragma unroll
    for (int m = 0; m < 4; ++m) {
        int r = m * 8 + sr;
        aR[m] = *(const floatx4*)&ain[(size_t)(row0 + r) * FEAT + IT0 * 32 + sk4];
        bR[m] = *(const floatx4*)&Wo[(size_t)(IT0 * 32 + r) * FEAT + col0 + sk4];
    }
    for (int it = IT0; it < IT1; ++it) {
        __syncthreads();
#pragma unroll
        for (int m = 0; m < 4; ++m) {
            int r = m * 8 + sr;
            AsT[w][sk4 + 0][r] = aR[m][0];
            AsT[w][sk4 + 1][r] = aR[m][1];
            AsT[w][sk4 + 2][r] = aR[m][2];
            AsT[w][sk4 + 3][r] = aR[m][3];
            *(floatx4*)&Bs[w][r][sk4] = bR[m];
        }
        __syncthreads();
        if (it + 1 < IT1) {
            int k0n = (it + 1) * 32;
#pragma unroll
            for (int m = 0; m < 4; ++m) {
                int r = m * 8 + sr;
                aR[m] = *(const floatx4*)&ain[(size_t)(row0 + r) * FEAT + k0n + sk4];
                bR[m] = *(const floatx4*)&Wo[(size_t)(k0n + r) * FEAT + col0 + sk4];
            }
        }
#pragma unroll
        for (int kk = 0; kk < 32; ++kk) {
            floatx4 a = *(const floatx4*)&AsT[w][kk][ty * 4];
            floatx4 b = *(const floatx4*)&Bs[w][kk][tx * 4];
#pragma unroll
            for (int i = 0; i < 4; ++i) acc[i] += a[i] * b;
        }
    }
    if (w == 1) {
#pragma unroll
        for (int i = 0; i < 4; ++i)
            *(floatx4*)&comb[ty * 4 + i][tx * 4] = acc[i];
    }
    __syncthreads();
    if (w == 0) {
#pragma unroll
        for (int i = 0; i < 4; ++i) {
            int row = row0 + ty * 4 + i;
            int c0 = col0 + tx * 4;
            floatx4 p = *(const floatx4*)&comb[ty * 4 + i][tx * 4];
            floatx4 a = acc[i] + p;
            floatx4 res = *(const floatx4*)&resid[(size_t)row * FEAT + c0];
            floatx4 o;
#pragma unroll
            for (int j = 0; j < 4; ++j) o[j] = res[j] + tanhf(a[j]);
            *(floatx4*)&xout[(size_t)row * FEAT + c0] = o;
            if (writeE) *(floatx4*)&ebufW[(size_t)row * INDP + c0] = o;
        }
    }
}

// ---------------- attn: q-tiled, bank-conflict-free, wave-parallel softmax ----------
__global__ __launch_bounds__(256)
void attn(const float* __restrict__ q, const float* __restrict__ k,
          const float* __restrict__ v, float* __restrict__ ao) {
    __shared__ float qs[16][80];
    __shared__ float ks[TT][81];
    __shared__ float vs[TT][81];
    __shared__ float sc[16][65];
    int bh = blockIdx.x;
    int b = bh >> 4, h = (bh >> 2) & 3, qt = bh & 3;
    int tid = threadIdx.x;
    for (int i = tid; i < TT * DH; i += 256) {
        int r = i / DH, d = i - r * DH;
        size_t base = (size_t)(b * TT + r) * FEAT + h * DH + d;
        ks[r][d] = k[base];
        vs[r][d] = v[base];
    }
    for (int i = tid; i < 16 * DH; i += 256) {
        int r = i / DH, d = i - r * DH;
        qs[r][d] = q[(size_t)(b * TT + qt * 16 + r) * FEAT + h * DH + d];
    }
    __syncthreads();
    const float scale = 0.11180339887498949f;   // 1/sqrt(80)
    for (int idx = tid; idx < 16 * 64; idx += 256) {
        int i = idx >> 6, j = idx & 63;
        float s = 0.f;
#pragma unroll 8
        for (int d = 0; d < DH; ++d) s += qs[i][d] * ks[j][d];
        sc[i][j] = s * scale;
    }
    __syncthreads();
    {
        int r = tid >> 4, l = tid & 15;
        int qi = qt * 16 + r;
        float p0, p1, p2, p3;
        int j0 = l, j1 = l + 16, j2 = l + 32, j3 = l + 48;
        p0 = (j0 < qi) ? sc[r][j0] : -1e30f;
        p1 = (j1 < qi) ? sc[r][j1] : -1e30f;
        p2 = (j2 < qi) ? sc[r][j2] : -1e30f;
        p3 = (j3 < qi) ? sc[r][j3] : -1e30f;
        float m = fmaxf(fmaxf(p0, p1), fmaxf(p2, p3));
#pragma unroll
        for (int off = 8; off; off >>= 1) m = fmaxf(m, __shfl_xor(m, off, 64));
        p0 = (j0 < qi) ? __expf(p0 - m) : 0.f;
        p1 = (j1 < qi) ? __expf(p1 - m) : 0.f;
        p2 = (j2 < qi) ? __expf(p2 - m) : 0.f;
        p3 = (j3 < qi) ? __expf(p3 - m) : 0.f;
        float sum = (p0 + p1) + (p2 + p3);
#pragma unroll
        for (int off = 8; off; off >>= 1) sum += __shfl_xor(sum, off, 64);
        float inv = (qi > 0) ? 1.0f / sum : 0.f;
        sc[r][j0] = p0 * inv;
        sc[r][j1] = p1 * inv;
        sc[r][j2] = p2 * inv;
        sc[r][j3] = p3 * inv;
    }
    __syncthreads();
    for (int idx = tid; idx < 16 * DH; idx += 256) {
        int i = idx / DH, d = idx - i * DH;
        float s = 0.f;
#pragma unroll 8
        for (int j = 0; j < TT; ++j) s += sc[i][j] * vs[j][d];
        ao[(size_t)(b * TT + qt * 16 + i) * FEAT + h * DH + d] = s;
    }
}

__global__ __launch_bounds__(128)
void score_k(const float* __restrict__ x, const float* __restrict__ W1,
             const float* __restrict__ b1, const float* __restrict__ W2,
             const float* __restrict__ b2, float* __restrict__ lam_out,
             float* __restrict__ loss_out) {
    __shared__ float xr[FEAT];
    __shared__ float red[2];
    int e = blockIdx.x;
    int tid = threadIdx.x;
    for (int f = tid; f < FEAT; f += 128) xr[f] = x[(size_t)e * FEAT + f];
    __syncthreads();
    int d = tid;
    float acc = b1[d];
    for (int kk = 0; kk < FEAT; ++kk) acc += xr[kk] * W1[kk * DD + d];
    acc = fmaxf(acc, 0.0f) * W2[d];
    for (int off = 32; off; off >>= 1) acc += __shfl_down(acc, off, 64);
    if ((tid & 63) == 0) red[tid >> 6] = acc;
    __syncthreads();
    if (tid == 0) {
        float s = red[0] + red[1] + b2[0];
        float lam = fmaxf(s, 0.0f) + log1pf(expf(-fabsf(s)));   // softplus
        lam_out[e] = lam;
        atomicAdd(loss_out, -logf(lam + 1e-8f) * (1.0f / 2048.0f));
    }
}

// ---------------- launch ----------------
extern "C" void kernel_launch(void* const* d_in, const int* in_sizes, int n_in,
                              void* d_out, int out_size, void* d_ws, size_t ws_size,
                              hipStream_t stream) {
    const int*   seq_s = (const int*)d_in[0];
    const int*   seq_o = (const int*)d_in[1];
    const int*   seq_r = (const int*)d_in[2];
    const float* seq_t = (const float*)d_in[3];
    const float* mem0  = (const float*)d_in[4];
    const float* lt0   = (const float*)d_in[5];
    const float* rel   = (const float*)d_in[6];
    const float* W_hidden = (const float*)d_in[7];
    const float* W_hh  = (const float*)d_in[8];
    const float* W_st  = (const float*)d_in[9];
    const float* W_ot  = (const float*)d_in[10];
    const float* Wq    = (const float*)d_in[11];
    const float* Wk    = (const float*)d_in[12];
    const float* Wv    = (const float*)d_in[13];
    const float* Wo    = (const float*)d_in[14];
    const float* sW1   = (const float*)d_in[15];
    const float* sb1   = (const float*)d_in[16];
    const float* sW2   = (const float*)d_in[17];
    const float* sb2   = (const float*)d_in[18];

    float* out      = (float*)d_out;
    float* out_lam  = out + 1;
    float* out_mem  = out + 2049;
    float* out_lt   = out + 2049 + (size_t)NE * DD;

    float* ws = (float*)d_ws;
    float* evt   = ws;                         // 655360
    float* xbuf  = ws + 655360;                // 655360
    float* ebuf  = ws + 1310720;               // 2048*512 = 1048576
    float* qbuf  = ws + 2359296;               // 655360
    float* kbuf  = ws + 3014656;               // 655360
    float* vbuf  = ws + 3670016;               // 655360
    float* aobuf = ws + 4325376;               // 655360
    float* slotDt   = ws + 4980736;            // 4096
    int*   slotPrev = (int*)(ws + 4984832);    // 4096
    int*   slotWin  = (int*)(ws + 4988928);    // 4096
    int*   fixList  = (int*)(ws + 4993024);    // 2048
    int*   fixState = (int*)(ws + 4995072);    // 2048
    int*   evFixIdx = (int*)(ws + 4997120);    // 2048
    int*   fixCnt   = (int*)(ws + 4999168);    // 1

    hipMemsetAsync(fixCnt, 0, sizeof(int), stream);
    hipMemsetAsync(out, 0, sizeof(float), stream);

    copy_init<<<2048, 256, 0, stream>>>(mem0, lt0, out_mem, out_lt);

    slot_analyze<<<NSLOT / 8, 256, 0, stream>>>(seq_s, seq_o, seq_t, lt0,
                                                slotDt, slotPrev, slotWin);
    fixlist_build<<<NEV / 256, 256, 0, stream>>>(slotPrev, fixList, fixState,
                                                 evFixIdx, fixCnt);
    event_compute<<<NEV / 4, 256, 0, stream>>>(seq_s, seq_o, seq_r, seq_t, mem0, rel,
                                               W_hidden, W_hh, W_st, W_ot, slotDt,
                                               evt, ebuf);
    for (int r = 0; r < 4; ++r)
        fix_round<<<64, 256, 0, stream>>>(r, seq_s, seq_o, mem0, W_hidden, W_hh,
                                          W_st, W_ot, slotDt, slotPrev,
                                          fixList, fixState, evFixIdx, fixCnt, evt, ebuf);
    scatter_win<<<512, 256, 0, stream>>>(seq_s, seq_o, seq_t, slotWin, evt, out_mem, out_lt);

    for (int l = 0; l < 2; ++l) {
        const float* src = l ? xbuf : evt;     // residual input
        proj<<<dim3(64, 10, 3), 128, 0, stream>>>(ebuf,
                                                  Wq + (size_t)l * IND * FEAT,
                                                  Wk + (size_t)l * IND * FEAT,
                                                  Wv + (size_t)l * IND * FEAT,
                                                  qbuf, kbuf, vbuf);
        attn<<<512, 256, 0, stream>>>(qbuf, kbuf, vbuf, aobuf);
        outproj<<<dim3(64, 10), 128, 0, stream>>>(aobuf, Wo + (size_t)l * FEAT * FEAT,
                                                  src, xbuf, ebuf, (l == 0) ? 1 : 0);
    }
    score_k<<<NEV, 128, 0, stream>>>(xbuf, sW1, sb1, sW2, sb2, out_lam, out);
}